// Round 7
// baseline (45.894 us; speedup 1.0000x reference)
//
#include <hip/hip_runtime.h>

#define CLS 512
#define NROWS 32768
#define WPB 4
#define NBLOCKS 2048   // 2048 blocks * 4 waves * 4 rows/wave = 32768 rows, one shot

// f32 add with DPP-shifted operand (VALU pipe, no DS/lgkmcnt).
template <int CTRL, int ROWM>
__device__ __forceinline__ float dpp_add(float x) {
  int s = __builtin_amdgcn_update_dpp(0, __float_as_int(x), CTRL, ROWM, 0xf, true);
  return x + __int_as_float(s);
}

// Standard wave64 sum: after this, lane 63 holds the full 64-lane sum.
__device__ __forceinline__ float wave_sum_dpp(float x) {
  x = dpp_add<0x111, 0xf>(x);  // row_shr:1
  x = dpp_add<0x112, 0xf>(x);  // row_shr:2
  x = dpp_add<0x114, 0xf>(x);  // row_shr:4
  x = dpp_add<0x118, 0xf>(x);  // row_shr:8
  x = dpp_add<0x142, 0xa>(x);  // row_bcast:15
  x = dpp_add<0x143, 0xc>(x);  // row_bcast:31 -> lane 63 = total
  return x;
}

__global__ __launch_bounds__(256) void lr_main_kernel(
    const float* __restrict__ out, const int* __restrict__ tgt,
    float* __restrict__ loss) {
  const int lane = threadIdx.x & 63;
  const int wid  = threadIdx.x >> 6;
  const int gw   = blockIdx.x * WPB + wid;          // 0..8191
  const size_t base = (size_t)gw * 4 * CLS;         // 4 consecutive rows per wave

  const float4* po = reinterpret_cast<const float4*>(out + base);
  const int4*   pt = reinterpret_cast<const int4*>(tgt + base);

  // 16 full-wave contiguous 1KB loads.
  float4 o[8];
  int4   t[8];
#pragma unroll
  for (int r = 0; r < 4; ++r) {
    o[2 * r]     = po[r * 128 + lane];
    o[2 * r + 1] = po[r * 128 + 64 + lane];
    t[2 * r]     = pt[r * 128 + lane];
    t[2 * r + 1] = pt[r * 128 + 64 + lane];
  }

  float acc = 0.0f;   // only lane 63's value is meaningful
#pragma unroll
  for (int r = 0; r < 4; ++r) {
    float s_neg = 0.0f, s_pos = 0.0f, np = 0.0f;
#pragma unroll
    for (int k = 0; k < 2; ++k) {
      float4 ov = o[2 * r + k];
      int4   tv = t[2 * r + k];
      float vx[4] = {ov.x, ov.y, ov.z, ov.w};
      int   mx[4] = {tv.x, tv.y, tv.z, tv.w};
#pragma unroll
      for (int j = 0; j < 4; ++j) {
        float e = __expf(mx[j] ? -vx[j] : vx[j]);
        s_pos += mx[j] ? e : 0.0f;
        s_neg += mx[j] ? 0.0f : e;
        np    += mx[j] ? 1.0f : 0.0f;
      }
    }
    s_neg = wave_sum_dpp(s_neg);
    s_pos = wave_sum_dpp(s_pos);
    np    = wave_sum_dpp(np);

    float num = np * ((float)CLS - np);
    if (num == 0.0f) num = (float)CLS;
    acc += s_neg * s_pos / num;     // valid in lane 63
  }

  __shared__ float sacc[WPB];
  if (lane == 63) sacc[wid] = acc;
  __syncthreads();
  if (threadIdx.x == 0) {
    // One relaxed device-scope atomic per block (2048 total), spread over
    // block completions. No fence semantics -> no cache-flush storm (the
    // R4 regression was the acq_rel release/acquire protocol, not atomics).
    atomicAdd(loss, sacc[0] + sacc[1] + sacc[2] + sacc[3]);
  }
}

extern "C" void kernel_launch(void* const* d_in, const int* in_sizes, int n_in,
                              void* d_out, int out_size, void* d_ws, size_t ws_size,
                              hipStream_t stream) {
  const float* output = (const float*)d_in[0];
  const int*   target = (const int*)d_in[1];
  float* loss = (float*)d_out;

  hipMemsetAsync(loss, 0, sizeof(float), stream);
  lr_main_kernel<<<NBLOCKS, 256, 0, stream>>>(output, target, loss);
}

// Round 8
// 26.977 us; speedup vs baseline: 1.7012x; 1.7012x over previous
//
#include <hip/hip_runtime.h>

#define CLS 512
#define NROWS 32768
#define WPB 4
#define NBLOCKS 4096   // 4096 blocks * 4 waves * 2 rows/wave = 32768 rows

// f32 add with DPP-shifted operand (VALU pipe, no DS/lgkmcnt).
template <int CTRL, int ROWM>
__device__ __forceinline__ float dpp_add(float x) {
  int s = __builtin_amdgcn_update_dpp(0, __float_as_int(x), CTRL, ROWM, 0xf, true);
  return x + __int_as_float(s);
}

// Standard wave64 sum: after this, lane 63 holds the full 64-lane sum.
__device__ __forceinline__ float wave_sum_dpp(float x) {
  x = dpp_add<0x111, 0xf>(x);  // row_shr:1
  x = dpp_add<0x112, 0xf>(x);  // row_shr:2
  x = dpp_add<0x114, 0xf>(x);  // row_shr:4
  x = dpp_add<0x118, 0xf>(x);  // row_shr:8
  x = dpp_add<0x142, 0xa>(x);  // row_bcast:15
  x = dpp_add<0x143, 0xc>(x);  // row_bcast:31 -> lane 63 = total
  return x;
}

__global__ __launch_bounds__(256) void lr_main_kernel(
    const float* __restrict__ out, const int* __restrict__ tgt,
    float* __restrict__ partial) {
  const int lane = threadIdx.x & 63;
  const int wid  = threadIdx.x >> 6;
  const int gw   = blockIdx.x * WPB + wid;          // 0..16383
  const size_t base = (size_t)gw * 2 * CLS;         // 2 consecutive rows per wave

  const float4* po = reinterpret_cast<const float4*>(out + base);
  const int4*   pt = reinterpret_cast<const int4*>(tgt + base);

  // 8 full-wave contiguous 1KB loads.
  float4 o[4];
  int4   t[4];
#pragma unroll
  for (int r = 0; r < 2; ++r) {
    o[2 * r]     = po[r * 128 + lane];
    o[2 * r + 1] = po[r * 128 + 64 + lane];
    t[2 * r]     = pt[r * 128 + lane];
    t[2 * r + 1] = pt[r * 128 + 64 + lane];
  }

  float acc = 0.0f;   // only lane 63's value is meaningful
#pragma unroll
  for (int r = 0; r < 2; ++r) {
    float s_neg = 0.0f, s_pos = 0.0f, np = 0.0f;
#pragma unroll
    for (int k = 0; k < 2; ++k) {
      float4 ov = o[2 * r + k];
      int4   tv = t[2 * r + k];
      float vx[4] = {ov.x, ov.y, ov.z, ov.w};
      int   mx[4] = {tv.x, tv.y, tv.z, tv.w};
#pragma unroll
      for (int j = 0; j < 4; ++j) {
        float e = __expf(mx[j] ? -vx[j] : vx[j]);
        s_pos += mx[j] ? e : 0.0f;
        s_neg += mx[j] ? 0.0f : e;
        np    += mx[j] ? 1.0f : 0.0f;
      }
    }
    s_neg = wave_sum_dpp(s_neg);
    s_pos = wave_sum_dpp(s_pos);
    np    = wave_sum_dpp(np);

    float num = np * ((float)CLS - np);
    if (num == 0.0f) num = (float)CLS;
    acc += s_neg * s_pos / num;     // valid in lane 63
  }

  __shared__ float sacc[WPB];
  if (lane == 63) sacc[wid] = acc;
  __syncthreads();
  if (threadIdx.x == 0)
    partial[blockIdx.x] = sacc[0] + sacc[1] + sacc[2] + sacc[3];
}

__global__ __launch_bounds__(1024) void lr_final_kernel(
    const float* __restrict__ partial, float* __restrict__ out) {
  const int lane = threadIdx.x & 63;
  const int wid  = threadIdx.x >> 6;   // 0..15

  float s = partial[threadIdx.x] + partial[threadIdx.x + 1024] +
            partial[threadIdx.x + 2048] + partial[threadIdx.x + 3072];
  s = wave_sum_dpp(s);                 // lane 63 of each wave

  __shared__ float w[16];
  if (lane == 63) w[wid] = s;
  __syncthreads();
  if (threadIdx.x == 0) {
    float tot = 0.0f;
#pragma unroll
    for (int i = 0; i < 16; ++i) tot += w[i];
    out[0] = tot;
  }
}

extern "C" void kernel_launch(void* const* d_in, const int* in_sizes, int n_in,
                              void* d_out, int out_size, void* d_ws, size_t ws_size,
                              hipStream_t stream) {
  const float* output = (const float*)d_in[0];
  const int*   target = (const int*)d_in[1];
  float* partial = (float*)d_ws;          // NBLOCKS floats = 16 KiB
  float* loss    = (float*)d_out;

  lr_main_kernel<<<NBLOCKS, 256, 0, stream>>>(output, target, partial);
  lr_final_kernel<<<1, 1024, 0, stream>>>(partial, loss);
}